// Round 1
// baseline (336.475 us; speedup 1.0000x reference)
//
#include <hip/hip_runtime.h>
#include <hip/hip_fp16.h>

#define B_  32
#define N_  256
#define HS_ 768
#define NH_ 32
#define D_  24
#define M_  (B_*N_)   // 8192

typedef unsigned short us8 __attribute__((ext_vector_type(8)));
typedef _Float16 f16x8 __attribute__((ext_vector_type(8)));
typedef float f32x4 __attribute__((ext_vector_type(4)));

__device__ __forceinline__ unsigned short f2h(float x){
  return __half_as_ushort(__float2half(x));
}
__device__ __forceinline__ float h2f(unsigned short u){
  return __half2float(__ushort_as_half(u));
}
__device__ __forceinline__ float dot4(float4 a, float4 b){
  return a.x*b.x + a.y*b.y + a.z*b.z + a.w*b.w;
}

// ---------------- fp32 -> fp16-bits conversion ----------------
__global__ __launch_bounds__(256) void cvt_kernel(const float* __restrict__ in,
                                                  unsigned short* __restrict__ out, int n4){
  int i = blockIdx.x*256 + threadIdx.x;
  if (i >= n4) return;
  float4 v = ((const float4*)in)[i];
  ushort4 o;
  o.x = f2h(v.x); o.y = f2h(v.y); o.z = f2h(v.z); o.w = f2h(v.w);
  ((ushort4*)out)[i] = o;
}

// ---------------- GEMM: C[m,n] = epi( sum_k A[m,k]*W[n,k] + bias[n] ) ----------------
// A: (M,K) fp16 bits row-major;  W: (N,K) fp16 bits row-major (i.e. B^T form)
// 64x64 tile, BK=32, 256 threads = 4 waves (2x2), each wave 32x32 via 4 MFMA tiles.
__device__ __forceinline__ void epi_tile(f32x4 acc, int row, int col, const float* __restrict__ bias,
                                         unsigned short* __restrict__ C, int N, int dogelu){
  float bv = bias[col];
#pragma unroll
  for (int r = 0; r < 4; r++){
    float v = acc[r] + bv;
    if (dogelu) v = 0.5f*v*(1.0f + erff(v*0.70710678118654752f));
    C[(size_t)(row + r)*N + col] = f2h(v);
  }
}

__global__ __launch_bounds__(256) void gemm_bt_kernel(
    const unsigned short* __restrict__ A, const unsigned short* __restrict__ W,
    const float* __restrict__ bias, unsigned short* __restrict__ C,
    int M, int N, int K, int dogelu)
{
  __shared__ unsigned short As[64][32];
  __shared__ unsigned short Bs[64][32];
  int tid = threadIdx.x;
  int nTiles = N >> 6;
  int tm = blockIdx.x / nTiles;
  int tn = blockIdx.x - tm*nTiles;
  int wave = tid >> 6, lane = tid & 63;
  int wm = ((wave >> 1) & 1) << 5;   // 0 or 32
  int wn = (wave & 1) << 5;          // 0 or 32
  int fr = lane & 15;
  int fk = (lane >> 4) << 3;         // 0,8,16,24
  int srow = tid >> 2;               // 0..63
  int scol = (tid & 3) << 3;         // 0,8,16,24
  const unsigned short* Ag = A + (size_t)(tm*64 + srow)*K + scol;
  const unsigned short* Wg = W + (size_t)(tn*64 + srow)*K + scol;

  f32x4 acc00 = {0.f,0.f,0.f,0.f};
  f32x4 acc01 = acc00, acc10 = acc00, acc11 = acc00;

  for (int k0 = 0; k0 < K; k0 += 32){
    *(us8*)&As[srow][scol] = *(const us8*)(Ag + k0);
    *(us8*)&Bs[srow][scol] = *(const us8*)(Wg + k0);
    __syncthreads();
    f16x8 a0 = __builtin_bit_cast(f16x8, *(const us8*)&As[wm + fr][fk]);
    f16x8 a1 = __builtin_bit_cast(f16x8, *(const us8*)&As[wm + 16 + fr][fk]);
    f16x8 b0 = __builtin_bit_cast(f16x8, *(const us8*)&Bs[wn + fr][fk]);
    f16x8 b1 = __builtin_bit_cast(f16x8, *(const us8*)&Bs[wn + 16 + fr][fk]);
    acc00 = __builtin_amdgcn_mfma_f32_16x16x32_f16(a0, b0, acc00, 0, 0, 0);
    acc01 = __builtin_amdgcn_mfma_f32_16x16x32_f16(a0, b1, acc01, 0, 0, 0);
    acc10 = __builtin_amdgcn_mfma_f32_16x16x32_f16(a1, b0, acc10, 0, 0, 0);
    acc11 = __builtin_amdgcn_mfma_f32_16x16x32_f16(a1, b1, acc11, 0, 0, 0);
    __syncthreads();
  }
  int r0 = tm*64 + wm + ((lane >> 4) << 2);
  int c0 = tn*64 + wn + fr;
  epi_tile(acc00, r0,      c0,      bias, C, N, dogelu);
  epi_tile(acc01, r0,      c0 + 16, bias, C, N, dogelu);
  epi_tile(acc10, r0 + 16, c0,      bias, C, N, dogelu);
  epi_tile(acc11, r0 + 16, c0 + 16, bias, C, N, dogelu);
}

// ---------------- attention + fused epilogue partials ----------------
// grid: B*NH*16 blocks; each block: one (b,h) and 16 query rows.
// f_part[b,h,i,c] = (1/rowsum) * sum_j exp(S[i,j]-m) * u_c[j] * dp[b,i,j,c]
#define ROWS 16
__global__ __launch_bounds__(256) void attn_kernel(
    const unsigned short* __restrict__ qb, const unsigned short* __restrict__ kb,
    const unsigned short* __restrict__ vb, const float* __restrict__ bias,
    const float* __restrict__ mask, const float* __restrict__ dp,
    const float* __restrict__ Wf1, const float* __restrict__ Wf2, const float* __restrict__ Wf3,
    float* __restrict__ fpart)
{
  int rb = blockIdx.x & 15;
  int bh = blockIdx.x >> 4;
  int h = bh & 31, b = bh >> 5;
  int i0 = rb * ROWS;
  int t = threadIdx.x;

  __shared__ __align__(16) float Ks[256][28];   // K rows fp32, padded stride 28
  __shared__ __align__(16) float Ss[ROWS][272]; // scores, padded stride 272
  __shared__ __align__(16) float Qs[ROWS][24];
  __shared__ float us[256][4];
  __shared__ float negv[256];

  // --- stage K row t, compute u[t][*], negv[t] ---
  {
    int j = t;
    size_t base = ((size_t)(b*N_ + j))*HS_ + h*D_;
    const us8* kp = (const us8*)(kb + base);
    us8 k0v = kp[0], k1v = kp[1], k2v = kp[2];
#pragma unroll
    for (int e = 0; e < 8; e++){
      Ks[j][e]     = h2f(k0v[e]);
      Ks[j][8+e]   = h2f(k1v[e]);
      Ks[j][16+e]  = h2f(k2v[e]);
    }
    const us8* vp = (const us8*)(vb + base);
    us8 v0v = vp[0], v1v = vp[1], v2v = vp[2];
    const float* wf1 = Wf1 + h*D_;
    const float* wf2 = Wf2 + h*D_;
    const float* wf3 = Wf3 + h*D_;
    float u0 = 0.f, u1 = 0.f, u2 = 0.f;
#pragma unroll
    for (int e = 0; e < 8; e++){
      float va = h2f(v0v[e]), vb2 = h2f(v1v[e]), vc = h2f(v2v[e]);
      u0 += va*wf1[e] + vb2*wf1[8+e] + vc*wf1[16+e];
      u1 += va*wf2[e] + vb2*wf2[8+e] + vc*wf2[16+e];
      u2 += va*wf3[e] + vb2*wf3[8+e] + vc*wf3[16+e];
    }
    us[j][0] = u0; us[j][1] = u1; us[j][2] = u2;
    negv[j] = (1.0f - mask[b*N_ + j]) * -100000.0f;
  }
  // --- stage Q rows ---
  for (int e = t; e < ROWS*D_; e += 256){
    int i = e / D_, d = e - i*D_;
    Qs[i][d] = h2f(qb[((size_t)(b*N_ + i0 + i))*HS_ + h*D_ + d]);
  }
  __syncthreads();

  int i = t >> 4, s = t & 15;   // 16 threads per query row
  float4 q0 = ((const float4*)Qs[i])[0];
  float4 q1 = ((const float4*)Qs[i])[1];
  float4 q2 = ((const float4*)Qs[i])[2];
  float4 q3 = ((const float4*)Qs[i])[3];
  float4 q4 = ((const float4*)Qs[i])[4];
  float4 q5 = ((const float4*)Qs[i])[5];

  // --- S = (q.k) * d^-0.5 ---
  for (int jj = 0; jj < 16; jj++){
    int j = s + 16*jj;
    const float4* kp = (const float4*)Ks[j];
    float sv = dot4(q0,kp[0]) + dot4(q1,kp[1]) + dot4(q2,kp[2])
             + dot4(q3,kp[3]) + dot4(q4,kp[4]) + dot4(q5,kp[5]);
    Ss[i][j] = sv * 0.2041241452319315f;   // 24^-0.5
  }
  __syncthreads();

  // --- += bias + neg (coalesced: thread t owns column t) ---
  {
    const float* bb = bias + (((size_t)(b*NH_ + h))*N_ + i0)*N_;
#pragma unroll 4
    for (int it = 0; it < ROWS; it++){
      Ss[it][t] += bb[it*N_ + t] + negv[t];
    }
  }
  __syncthreads();

  // --- softmax (normalization deferred to the end) ---
  float m = -1e30f;
  for (int jj = 0; jj < 16; jj++) m = fmaxf(m, Ss[i][s + 16*jj]);
  m = fmaxf(m, __shfl_xor(m, 1));
  m = fmaxf(m, __shfl_xor(m, 2));
  m = fmaxf(m, __shfl_xor(m, 4));
  m = fmaxf(m, __shfl_xor(m, 8));
  float sum = 0.f;
  for (int jj = 0; jj < 16; jj++){
    int j = s + 16*jj;
    float e = __expf(Ss[i][j] - m);
    Ss[i][j] = e;
    sum += e;
  }
  sum += __shfl_xor(sum, 1);
  sum += __shfl_xor(sum, 2);
  sum += __shfl_xor(sum, 4);
  sum += __shfl_xor(sum, 8);
  float rs = 1.0f / sum;

  // --- fused epilogue partials (reads own slice; no barrier needed) ---
  {
    float a0 = 0.f, a1 = 0.f, a2 = 0.f;
    const float* dpb = dp + ((size_t)(b*N_ + i0 + i))*N_*3;
    for (int jj = 0; jj < 16; jj++){
      int j = s + 16*jj;
      float p = Ss[i][j];
      float d0 = dpb[j*3], d1 = dpb[j*3+1], d2 = dpb[j*3+2];
      a0 += p*us[j][0]*d0;
      a1 += p*us[j][1]*d1;
      a2 += p*us[j][2]*d2;
    }
    a0 += __shfl_xor(a0, 1); a0 += __shfl_xor(a0, 2); a0 += __shfl_xor(a0, 4); a0 += __shfl_xor(a0, 8);
    a1 += __shfl_xor(a1, 1); a1 += __shfl_xor(a1, 2); a1 += __shfl_xor(a1, 4); a1 += __shfl_xor(a1, 8);
    a2 += __shfl_xor(a2, 1); a2 += __shfl_xor(a2, 2); a2 += __shfl_xor(a2, 4); a2 += __shfl_xor(a2, 8);
    if (s == 0){
      float* fp = fpart + (((size_t)(b*NH_ + h))*N_ + i0 + i)*3;
      fp[0] = a0*rs; fp[1] = a1*rs; fp[2] = a2*rs;
    }
  }
}

// ---------------- final cross-head reduction ----------------
__global__ __launch_bounds__(256) void final_kernel(const float* __restrict__ fpart,
    const float* __restrict__ bf1, const float* __restrict__ bf2, const float* __restrict__ bf3,
    float* __restrict__ out)
{
  int idx = blockIdx.x*256 + threadIdx.x;
  if (idx >= B_*N_*3) return;
  int c = idx % 3;
  int bi = idx / 3;
  int b = bi >> 8, ii = bi & 255;
  float sacc = (c == 0) ? bf1[0] : (c == 1) ? bf2[0] : bf3[0];
#pragma unroll 8
  for (int hh = 0; hh < NH_; hh++){
    sacc += fpart[(((size_t)(b*NH_ + hh))*N_ + ii)*3 + c];
  }
  out[idx] = sacc;
}

extern "C" void kernel_launch(void* const* d_in, const int* in_sizes, int n_in,
                              void* d_out, int out_size, void* d_ws, size_t ws_size,
                              hipStream_t stream)
{
  const float* X    = (const float*)d_in[0];
  const float* bias = (const float*)d_in[1];
  const float* dp   = (const float*)d_in[2];
  const float* mask = (const float*)d_in[3];
  const float* Wi   = (const float*)d_in[4];
  const float* bi   = (const float*)d_in[5];
  const float* Wq   = (const float*)d_in[6];
  const float* bq   = (const float*)d_in[7];
  const float* Wk   = (const float*)d_in[8];
  const float* bk   = (const float*)d_in[9];
  const float* Wv   = (const float*)d_in[10];
  const float* bv   = (const float*)d_in[11];
  const float* Wf1  = (const float*)d_in[12];
  const float* bf1  = (const float*)d_in[13];
  const float* Wf2  = (const float*)d_in[14];
  const float* bf2  = (const float*)d_in[15];
  const float* Wf3  = (const float*)d_in[16];
  const float* bf3  = (const float*)d_in[17];
  float* out = (float*)d_out;

  unsigned short* xb  = (unsigned short*)d_ws;
  unsigned short* wib = xb  + (size_t)M_*HS_;
  unsigned short* wqb = wib + (size_t)HS_*HS_;
  unsigned short* wkb = wqb + (size_t)HS_*HS_;
  unsigned short* wvb = wkb + (size_t)HS_*HS_;
  unsigned short* hb  = wvb + (size_t)HS_*HS_;
  unsigned short* qb  = hb  + (size_t)M_*HS_;
  unsigned short* kb  = qb  + (size_t)M_*HS_;
  unsigned short* vb  = kb  + (size_t)M_*HS_;
  float* fpart = (float*)(vb + (size_t)M_*HS_);

  // converts
  {
    int n4 = M_*HS_/4;          // 1572864
    cvt_kernel<<<n4/256, 256, 0, stream>>>(X, xb, n4);
    int w4 = HS_*HS_/4;         // 147456
    cvt_kernel<<<w4/256, 256, 0, stream>>>(Wi, wib, w4);
    cvt_kernel<<<w4/256, 256, 0, stream>>>(Wq, wqb, w4);
    cvt_kernel<<<w4/256, 256, 0, stream>>>(Wk, wkb, w4);
    cvt_kernel<<<w4/256, 256, 0, stream>>>(Wv, wvb, w4);
  }

  dim3 ggrid((M_/64)*(HS_/64));   // 128*12 = 1536
  // h = gelu(X Wi^T + bi)
  gemm_bt_kernel<<<ggrid, 256, 0, stream>>>(xb, wib, bi, hb, M_, HS_, HS_, 1);
  // q,k,v = h W^T + b
  gemm_bt_kernel<<<ggrid, 256, 0, stream>>>(hb, wqb, bq, qb, M_, HS_, HS_, 0);
  gemm_bt_kernel<<<ggrid, 256, 0, stream>>>(hb, wkb, bk, kb, M_, HS_, HS_, 0);
  gemm_bt_kernel<<<ggrid, 256, 0, stream>>>(hb, wvb, bv, vb, M_, HS_, HS_, 0);

  attn_kernel<<<B_*NH_*16, 256, 0, stream>>>(qb, kb, vb, bias, mask, dp,
                                             Wf1, Wf2, Wf3, fpart);

  final_kernel<<<(B_*N_*3 + 255)/256, 256, 0, stream>>>(fpart, bf1, bf2, bf3, out);
}

// Round 2
// 307.496 us; speedup vs baseline: 1.0942x; 1.0942x over previous
//
#include <hip/hip_runtime.h>
#include <hip/hip_fp16.h>

#define B_  32
#define N_  256
#define HS_ 768
#define NH_ 32
#define D_  24
#define M_  (B_*N_)   // 8192
#define QKVN 2304

typedef unsigned short us8 __attribute__((ext_vector_type(8)));
typedef _Float16 f16x8 __attribute__((ext_vector_type(8)));
typedef float f32x4 __attribute__((ext_vector_type(4)));

__device__ __forceinline__ unsigned short f2h(float x){
  return __half_as_ushort(__float2half(x));
}
__device__ __forceinline__ float h2f(unsigned short u){
  return __half2float(__ushort_as_half(u));
}

// ---------------- fp32 -> fp16-bits conversion ----------------
__global__ __launch_bounds__(256) void cvt_kernel(const float* __restrict__ in,
                                                  unsigned short* __restrict__ out, int n4){
  int i = blockIdx.x*256 + threadIdx.x;
  if (i >= n4) return;
  float4 v = ((const float4*)in)[i];
  ushort4 o;
  o.x = f2h(v.x); o.y = f2h(v.y); o.z = f2h(v.z); o.w = f2h(v.w);
  ((ushort4*)out)[i] = o;
}

// ---------------- GEMM: C[m,n] = epi( sum_k A[m,k]*W[n,k] + bias[n] ) ----------------
// A: (M,K) fp16 bits row-major;  W: (N,K) fp16 bits row-major.
// bias selected from {b0,b1,b2} by col/768 (for fused qkv GEMM; pass same ptr 3x otherwise).
__device__ __forceinline__ void epi_tile(f32x4 acc, int row, int col, const float* __restrict__ bias,
                                         unsigned short* __restrict__ C, int N, int dogelu){
  float bv = bias[col];
#pragma unroll
  for (int r = 0; r < 4; r++){
    float v = acc[r] + bv;
    if (dogelu) v = 0.5f*v*(1.0f + erff(v*0.70710678118654752f));
    C[(size_t)(row + r)*N + col] = f2h(v);
  }
}

__global__ __launch_bounds__(256) void gemm_bt_kernel(
    const unsigned short* __restrict__ A, const unsigned short* __restrict__ W,
    const float* __restrict__ b0, const float* __restrict__ b1, const float* __restrict__ b2,
    unsigned short* __restrict__ C, int M, int N, int K, int dogelu)
{
  __shared__ unsigned short As[64][32];
  __shared__ unsigned short Bs[64][32];
  int tid = threadIdx.x;
  int nTiles = N >> 6;
  int tm = blockIdx.x / nTiles;
  int tn = blockIdx.x - tm*nTiles;
  int which = (tn << 6) / 768;
  const float* bp = (which == 0) ? b0 : (which == 1) ? b1 : b2;
  bp -= which * 768;   // epi indexes by global col
  int wave = tid >> 6, lane = tid & 63;
  int wm = ((wave >> 1) & 1) << 5;
  int wn = (wave & 1) << 5;
  int fr = lane & 15;
  int fk = (lane >> 4) << 3;
  int srow = tid >> 2;
  int scol = (tid & 3) << 3;
  const unsigned short* Ag = A + (size_t)(tm*64 + srow)*K + scol;
  const unsigned short* Wg = W + (size_t)(tn*64 + srow)*K + scol;

  f32x4 acc00 = {0.f,0.f,0.f,0.f};
  f32x4 acc01 = acc00, acc10 = acc00, acc11 = acc00;

  for (int k0 = 0; k0 < K; k0 += 32){
    *(us8*)&As[srow][scol] = *(const us8*)(Ag + k0);
    *(us8*)&Bs[srow][scol] = *(const us8*)(Wg + k0);
    __syncthreads();
    f16x8 a0 = __builtin_bit_cast(f16x8, *(const us8*)&As[wm + fr][fk]);
    f16x8 a1 = __builtin_bit_cast(f16x8, *(const us8*)&As[wm + 16 + fr][fk]);
    f16x8 b0v = __builtin_bit_cast(f16x8, *(const us8*)&Bs[wn + fr][fk]);
    f16x8 b1v = __builtin_bit_cast(f16x8, *(const us8*)&Bs[wn + 16 + fr][fk]);
    acc00 = __builtin_amdgcn_mfma_f32_16x16x32_f16(a0, b0v, acc00, 0, 0, 0);
    acc01 = __builtin_amdgcn_mfma_f32_16x16x32_f16(a0, b1v, acc01, 0, 0, 0);
    acc10 = __builtin_amdgcn_mfma_f32_16x16x32_f16(a1, b0v, acc10, 0, 0, 0);
    acc11 = __builtin_amdgcn_mfma_f32_16x16x32_f16(a1, b1v, acc11, 0, 0, 0);
    __syncthreads();
  }
  int r0 = tm*64 + wm + ((lane >> 4) << 2);
  int c0 = tn*64 + wn + fr;
  epi_tile(acc00, r0,      c0,      bp, C, N, dogelu);
  epi_tile(acc01, r0,      c0 + 16, bp, C, N, dogelu);
  epi_tile(acc10, r0 + 16, c0,      bp, C, N, dogelu);
  epi_tile(acc11, r0 + 16, c0 + 16, bp, C, N, dogelu);
}

// ---------------- attention + fused epilogue partials (MFMA scores) ----------------
// grid: B*NH*4; each block: one (b,h), 64 query rows, 4 waves (16 rows/wave).
// S^T layout via mfma(K,Q): lane holds i = w*16 + (lane&15), j = 16*jt + (lane>>4)*4 + r.
#define SCALE 0.20412414523193154f  // 24^-0.5
__global__ __launch_bounds__(256) void attn_kernel(
    const unsigned short* __restrict__ qkv,   // [M][2304]: q|k|v
    const float* __restrict__ bias, const float* __restrict__ mask,
    const float* __restrict__ dp,
    const float* __restrict__ Wf1, const float* __restrict__ Wf2, const float* __restrict__ Wf3,
    float* __restrict__ fpart)
{
  int rb = blockIdx.x & 3;
  int bh = blockIdx.x >> 2;
  int h = bh & 31, b = bh >> 5;
  int i0 = rb * 64;
  int t = threadIdx.x;

  __shared__ us8 Kp[256][4];      // fp16, k padded to 32 (chunk 3 = zeros); 16 KB
  __shared__ us8 Qp[64][4];       // 4 KB
  __shared__ float4 uu[256];      // (u0,u1,u2,-)
  __shared__ float negs[256];

  // --- stage K row t, compute u[t], neg[t] ---
  {
    int j = t;
    const unsigned short* kr = qkv + (size_t)(b*N_ + j)*QKVN + 768 + h*D_;
    us8 z = {0,0,0,0,0,0,0,0};
    Kp[j][0] = *(const us8*)(kr);
    Kp[j][1] = *(const us8*)(kr + 8);
    Kp[j][2] = *(const us8*)(kr + 16);
    Kp[j][3] = z;
    const unsigned short* vr = qkv + (size_t)(b*N_ + j)*QKVN + 1536 + h*D_;
    us8 v0 = *(const us8*)(vr);
    us8 v1 = *(const us8*)(vr + 8);
    us8 v2 = *(const us8*)(vr + 16);
    const float* w1 = Wf1 + h*D_;
    const float* w2 = Wf2 + h*D_;
    const float* w3 = Wf3 + h*D_;
    float u0 = 0.f, u1 = 0.f, u2 = 0.f;
#pragma unroll
    for (int e = 0; e < 8; e++){
      float va = h2f(v0[e]), vb2 = h2f(v1[e]), vc = h2f(v2[e]);
      u0 += va*w1[e] + vb2*w1[8+e] + vc*w1[16+e];
      u1 += va*w2[e] + vb2*w2[8+e] + vc*w2[16+e];
      u2 += va*w3[e] + vb2*w3[8+e] + vc*w3[16+e];
    }
    uu[j] = make_float4(u0, u1, u2, 0.f);
    negs[j] = (1.0f - mask[b*N_ + j]) * -100000.0f;
  }
  // --- stage Q rows (64 rows x 4 chunks) ---
  {
    int i = t >> 2, part = t & 3;
    const unsigned short* qr = qkv + (size_t)(b*N_ + i0 + i)*QKVN + h*D_;
    us8 z = {0,0,0,0,0,0,0,0};
    Qp[i][part] = (part < 3) ? *(const us8*)(qr + part*8) : z;
  }
  __syncthreads();

  int wave = t >> 6, lane = t & 63;
  int fr = lane & 15, g = lane >> 4;
  int i = wave*16 + fr;             // local query row

  // --- scores via MFMA: s[jt][r] = S[i, jt*16 + g*4 + r] ---
  f16x8 qf = __builtin_bit_cast(f16x8, Qp[i][g]);
  f32x4 s[16];
#pragma unroll
  for (int jt = 0; jt < 16; jt++){
    f16x8 kf = __builtin_bit_cast(f16x8, Kp[jt*16 + fr][g]);
    f32x4 zz = {0.f,0.f,0.f,0.f};
    s[jt] = __builtin_amdgcn_mfma_f32_16x16x32_f16(kf, qf, zz, 0, 0, 0);
  }

  // --- scale + bias + mask, row max ---
  const float4* bb4 = (const float4*)(bias + ((size_t)(b*NH_ + h)*N_ + i0 + i)*N_);
  float m = -1e30f;
#pragma unroll
  for (int jt = 0; jt < 16; jt++){
    float4 bv = bb4[jt*4 + g];
    float4 nv = *(const float4*)&negs[jt*16 + g*4];
    s[jt][0] = fmaf(s[jt][0], SCALE, bv.x + nv.x);
    s[jt][1] = fmaf(s[jt][1], SCALE, bv.y + nv.y);
    s[jt][2] = fmaf(s[jt][2], SCALE, bv.z + nv.z);
    s[jt][3] = fmaf(s[jt][3], SCALE, bv.w + nv.w);
    m = fmaxf(m, fmaxf(fmaxf(s[jt][0], s[jt][1]), fmaxf(s[jt][2], s[jt][3])));
  }
  m = fmaxf(m, __shfl_xor(m, 16));
  m = fmaxf(m, __shfl_xor(m, 32));

  // --- exp + sum ---
  float sum = 0.f;
#pragma unroll
  for (int jt = 0; jt < 16; jt++){
#pragma unroll
    for (int r = 0; r < 4; r++){
      float e = __expf(s[jt][r] - m);
      s[jt][r] = e;
      sum += e;
    }
  }
  sum += __shfl_xor(sum, 16);
  sum += __shfl_xor(sum, 32);
  float rs = 1.0f / sum;

  // --- fused epilogue: a_c = sum_j p * u_c[j] * dp[b,i,j,c] ---
  const float* dpb = dp + (size_t)(b*N_ + i0 + i) * (N_*3);
  float a0 = 0.f, a1 = 0.f, a2 = 0.f;
#pragma unroll
  for (int jt = 0; jt < 16; jt++){
    int j0 = jt*16 + g*4;
    const float4* dq = (const float4*)(dpb + j0*3);
    float4 d0 = dq[0], d1 = dq[1], d2 = dq[2];
    float4 u0v = uu[j0], u1v = uu[j0+1], u2v = uu[j0+2], u3v = uu[j0+3];
    float p0 = s[jt][0], p1 = s[jt][1], p2 = s[jt][2], p3 = s[jt][3];
    a0 += p0*u0v.x*d0.x + p1*u1v.x*d0.w + p2*u2v.x*d1.z + p3*u3v.x*d2.y;
    a1 += p0*u0v.y*d0.y + p1*u1v.y*d1.x + p2*u2v.y*d1.w + p3*u3v.y*d2.z;
    a2 += p0*u0v.z*d0.z + p1*u1v.z*d1.y + p2*u2v.z*d2.x + p3*u3v.z*d2.w;
  }
  a0 += __shfl_xor(a0, 16); a0 += __shfl_xor(a0, 32);
  a1 += __shfl_xor(a1, 16); a1 += __shfl_xor(a1, 32);
  a2 += __shfl_xor(a2, 16); a2 += __shfl_xor(a2, 32);
  if (lane < 16){
    float* fp = fpart + ((size_t)(b*NH_ + h)*N_ + i0 + i)*3;
    fp[0] = a0*rs; fp[1] = a1*rs; fp[2] = a2*rs;
  }
}

// ---------------- final cross-head reduction ----------------
__global__ __launch_bounds__(256) void final_kernel(const float* __restrict__ fpart,
    const float* __restrict__ bf1, const float* __restrict__ bf2, const float* __restrict__ bf3,
    float* __restrict__ out)
{
  int idx = blockIdx.x*256 + threadIdx.x;
  if (idx >= B_*N_*3) return;
  int c = idx % 3;
  int bi = idx / 3;
  int b = bi >> 8, ii = bi & 255;
  float sacc = (c == 0) ? bf1[0] : (c == 1) ? bf2[0] : bf3[0];
#pragma unroll 8
  for (int hh = 0; hh < NH_; hh++){
    sacc += fpart[(((size_t)(b*NH_ + hh))*N_ + ii)*3 + c];
  }
  out[idx] = sacc;
}

extern "C" void kernel_launch(void* const* d_in, const int* in_sizes, int n_in,
                              void* d_out, int out_size, void* d_ws, size_t ws_size,
                              hipStream_t stream)
{
  const float* X    = (const float*)d_in[0];
  const float* bias = (const float*)d_in[1];
  const float* dp   = (const float*)d_in[2];
  const float* mask = (const float*)d_in[3];
  const float* Wi   = (const float*)d_in[4];
  const float* bi   = (const float*)d_in[5];
  const float* Wq   = (const float*)d_in[6];
  const float* bq   = (const float*)d_in[7];
  const float* Wk   = (const float*)d_in[8];
  const float* bk   = (const float*)d_in[9];
  const float* Wv   = (const float*)d_in[10];
  const float* bv   = (const float*)d_in[11];
  const float* Wf1  = (const float*)d_in[12];
  const float* bf1  = (const float*)d_in[13];
  const float* Wf2  = (const float*)d_in[14];
  const float* bf2  = (const float*)d_in[15];
  const float* Wf3  = (const float*)d_in[16];
  const float* bf3  = (const float*)d_in[17];
  float* out = (float*)d_out;

  unsigned short* xb   = (unsigned short*)d_ws;
  unsigned short* wib  = xb   + (size_t)M_*HS_;
  unsigned short* wqb  = wib  + (size_t)HS_*HS_;
  unsigned short* wkb  = wqb  + (size_t)HS_*HS_;
  unsigned short* wvb  = wkb  + (size_t)HS_*HS_;
  unsigned short* hb   = wvb  + (size_t)HS_*HS_;
  unsigned short* qkvb = hb   + (size_t)M_*HS_;
  float* fpart = (float*)(qkvb + (size_t)M_*QKVN);

  // converts
  {
    int n4 = M_*HS_/4;
    cvt_kernel<<<n4/256, 256, 0, stream>>>(X, xb, n4);
    int w4 = HS_*HS_/4;
    cvt_kernel<<<w4/256, 256, 0, stream>>>(Wi, wib, w4);
    cvt_kernel<<<w4/256, 256, 0, stream>>>(Wq, wqb, w4);
    cvt_kernel<<<w4/256, 256, 0, stream>>>(Wk, wkb, w4);
    cvt_kernel<<<w4/256, 256, 0, stream>>>(Wv, wvb, w4);
  }

  // h = gelu(X Wi^T + bi)
  gemm_bt_kernel<<<(M_/64)*(HS_/64), 256, 0, stream>>>(xb, wib, bi, bi, bi, hb, M_, HS_, HS_, 1);
  // qkv = h [Wq;Wk;Wv]^T + [bq;bk;bv]   (N = 2304)
  gemm_bt_kernel<<<(M_/64)*(QKVN/64), 256, 0, stream>>>(hb, wqb, bq, bk, bv, qkvb, M_, QKVN, HS_, 0);

  attn_kernel<<<B_*NH_*4, 256, 0, stream>>>(qkvb, bias, mask, dp, Wf1, Wf2, Wf3, fpart);

  final_kernel<<<(B_*N_*3 + 255)/256, 256, 0, stream>>>(fpart, bf1, bf2, bf3, out);
}

// Round 3
// 277.851 us; speedup vs baseline: 1.2110x; 1.1067x over previous
//
#include <hip/hip_runtime.h>
#include <hip/hip_fp16.h>

#define B_  32
#define N_  256
#define HS_ 768
#define NH_ 32
#define D_  24
#define M_  (B_*N_)   // 8192
#define QKVN 2304

typedef unsigned short us8 __attribute__((ext_vector_type(8)));
typedef _Float16 f16x8 __attribute__((ext_vector_type(8)));
typedef float f32x4 __attribute__((ext_vector_type(4)));

__device__ __forceinline__ unsigned short f2h(float x){
  return __half_as_ushort(__float2half(x));
}
__device__ __forceinline__ float h2f(unsigned short u){
  return __half2float(__ushort_as_half(u));
}

// ---------------- fp32 -> fp16-bits conversion ----------------
__global__ __launch_bounds__(256) void cvt_kernel(const float* __restrict__ in,
                                                  unsigned short* __restrict__ out, int n4){
  int i = blockIdx.x*256 + threadIdx.x;
  if (i >= n4) return;
  float4 v = ((const float4*)in)[i];
  ushort4 o;
  o.x = f2h(v.x); o.y = f2h(v.y); o.z = f2h(v.z); o.w = f2h(v.w);
  ((ushort4*)out)[i] = o;
}

// ---------------- GEMM: C[m,n] = epi( sum_k A[m,k]*W[n,k] + bias[n] ) ----------------
__device__ __forceinline__ void epi_tile(f32x4 acc, int row, int col, const float* __restrict__ bias,
                                         unsigned short* __restrict__ C, int N, int dogelu){
  float bv = bias[col];
#pragma unroll
  for (int r = 0; r < 4; r++){
    float v = acc[r] + bv;
    if (dogelu) v = 0.5f*v*(1.0f + erff(v*0.70710678118654752f));
    C[(size_t)(row + r)*N + col] = f2h(v);
  }
}

__global__ __launch_bounds__(256) void gemm_bt_kernel(
    const unsigned short* __restrict__ A, const unsigned short* __restrict__ W,
    const float* __restrict__ b0, const float* __restrict__ b1, const float* __restrict__ b2,
    unsigned short* __restrict__ C, int M, int N, int K, int dogelu)
{
  __shared__ unsigned short As[64][32];
  __shared__ unsigned short Bs[64][32];
  int tid = threadIdx.x;
  int nTiles = N >> 6;
  int tm = blockIdx.x / nTiles;
  int tn = blockIdx.x - tm*nTiles;
  int which = (tn << 6) / 768;
  const float* bp = (which == 0) ? b0 : (which == 1) ? b1 : b2;
  bp -= which * 768;
  int wave = tid >> 6, lane = tid & 63;
  int wm = ((wave >> 1) & 1) << 5;
  int wn = (wave & 1) << 5;
  int fr = lane & 15;
  int fk = (lane >> 4) << 3;
  int srow = tid >> 2;
  int scol = (tid & 3) << 3;
  const unsigned short* Ag = A + (size_t)(tm*64 + srow)*K + scol;
  const unsigned short* Wg = W + (size_t)(tn*64 + srow)*K + scol;

  f32x4 acc00 = {0.f,0.f,0.f,0.f};
  f32x4 acc01 = acc00, acc10 = acc00, acc11 = acc00;

  for (int k0 = 0; k0 < K; k0 += 32){
    *(us8*)&As[srow][scol] = *(const us8*)(Ag + k0);
    *(us8*)&Bs[srow][scol] = *(const us8*)(Wg + k0);
    __syncthreads();
    f16x8 a0 = __builtin_bit_cast(f16x8, *(const us8*)&As[wm + fr][fk]);
    f16x8 a1 = __builtin_bit_cast(f16x8, *(const us8*)&As[wm + 16 + fr][fk]);
    f16x8 b0v = __builtin_bit_cast(f16x8, *(const us8*)&Bs[wn + fr][fk]);
    f16x8 b1v = __builtin_bit_cast(f16x8, *(const us8*)&Bs[wn + 16 + fr][fk]);
    acc00 = __builtin_amdgcn_mfma_f32_16x16x32_f16(a0, b0v, acc00, 0, 0, 0);
    acc01 = __builtin_amdgcn_mfma_f32_16x16x32_f16(a0, b1v, acc01, 0, 0, 0);
    acc10 = __builtin_amdgcn_mfma_f32_16x16x32_f16(a1, b0v, acc10, 0, 0, 0);
    acc11 = __builtin_amdgcn_mfma_f32_16x16x32_f16(a1, b1v, acc11, 0, 0, 0);
    __syncthreads();
  }
  int r0 = tm*64 + wm + ((lane >> 4) << 2);
  int c0 = tn*64 + wn + fr;
  epi_tile(acc00, r0,      c0,      bp, C, N, dogelu);
  epi_tile(acc01, r0,      c0 + 16, bp, C, N, dogelu);
  epi_tile(acc10, r0 + 16, c0,      bp, C, N, dogelu);
  epi_tile(acc11, r0 + 16, c0 + 16, bp, C, N, dogelu);
}

// ---------------- attention + fused epilogue partials ----------------
// grid: B*NH*4 blocks of 512 thr (8 waves). Block: one (b,h), 64 query rows.
// wave w: row group rg=w>>1 (16 rows), col half ch=w&1 (128 cols).
// mfma(K,Q): lane(fr,g) holds i=rg*16+fr, j=ch*128+jt*16+g*4+r, jt=0..7.
#define SCALE 0.20412414523193154f  // 24^-0.5
__global__ __launch_bounds__(512, 4) void attn_kernel(
    const unsigned short* __restrict__ qkv,   // [M][2304]: q|k|v
    const float* __restrict__ bias, const float* __restrict__ mask,
    const float* __restrict__ dp,
    const float* __restrict__ Wf1, const float* __restrict__ Wf2, const float* __restrict__ Wf3,
    float* __restrict__ fpart)
{
  int rb = blockIdx.x & 3;
  int bh = blockIdx.x >> 2;
  int h = bh & 31, b = bh >> 5;
  int i0 = rb * 64;
  int t = threadIdx.x;

  __shared__ us8 Kp[256][5];      // fp16 K rows padded to 5 chunks (chunk3=0) -> 20 KB
  __shared__ us8 Qp[64][5];       // 5 KB
  __shared__ float u0s[256], u1s[256], u2s[256];
  __shared__ float negs[256];
  __shared__ float redm[4][16][2];     // per (rg,fr,ch) partial max
  __shared__ float4 redv[4][16][2];    // (sum,a0,a1,a2)

  if (t < 256){
    // --- stage K row t, compute u[t], neg[t] ---
    int j = t;
    const unsigned short* kr = qkv + (size_t)(b*N_ + j)*QKVN + 768 + h*D_;
    us8 z = {0,0,0,0,0,0,0,0};
    Kp[j][0] = *(const us8*)(kr);
    Kp[j][1] = *(const us8*)(kr + 8);
    Kp[j][2] = *(const us8*)(kr + 16);
    Kp[j][3] = z;
    const unsigned short* vr = kr + 768;
    us8 v0 = *(const us8*)(vr);
    us8 v1 = *(const us8*)(vr + 8);
    us8 v2 = *(const us8*)(vr + 16);
    const float* w1 = Wf1 + h*D_;
    const float* w2 = Wf2 + h*D_;
    const float* w3 = Wf3 + h*D_;
    float u0 = 0.f, u1 = 0.f, u2 = 0.f;
#pragma unroll
    for (int e = 0; e < 8; e++){
      float va = h2f(v0[e]), vb2 = h2f(v1[e]), vc = h2f(v2[e]);
      u0 += va*w1[e] + vb2*w1[8+e] + vc*w1[16+e];
      u1 += va*w2[e] + vb2*w2[8+e] + vc*w2[16+e];
      u2 += va*w3[e] + vb2*w3[8+e] + vc*w3[16+e];
    }
    u0s[j] = u0; u1s[j] = u1; u2s[j] = u2;
    negs[j] = (1.0f - mask[b*N_ + j]) * -100000.0f;
  } else {
    // --- stage Q rows (64 rows x 4 chunks) ---
    int tq = t - 256;
    int i = tq >> 2, part = tq & 3;
    const unsigned short* qr = qkv + (size_t)(b*N_ + i0 + i)*QKVN + h*D_;
    us8 z = {0,0,0,0,0,0,0,0};
    Qp[i][part] = (part < 3) ? *(const us8*)(qr + part*8) : z;
  }
  __syncthreads();

  int wave = t >> 6, lane = t & 63;
  int rg = wave >> 1, ch = wave & 1;
  int fr = lane & 15, g = lane >> 4;
  int i = rg*16 + fr;               // local query row 0..63

  // --- prefetch bias (8 float4, issued before MFMA loop) ---
  const float4* bias4 = (const float4*)(bias + ((size_t)(b*NH_ + h)*N_ + i0 + i)*N_ + ch*128);
  float4 bvv[8];
#pragma unroll
  for (int jt = 0; jt < 8; jt++) bvv[jt] = bias4[jt*4 + g];

  // --- scores via MFMA ---
  f16x8 qf = __builtin_bit_cast(f16x8, Qp[i][g]);
  f32x4 s[8];
#pragma unroll
  for (int jt = 0; jt < 8; jt++){
    f16x8 kf = __builtin_bit_cast(f16x8, Kp[ch*128 + jt*16 + fr][g]);
    f32x4 zz = {0.f,0.f,0.f,0.f};
    s[jt] = __builtin_amdgcn_mfma_f32_16x16x32_f16(kf, qf, zz, 0, 0, 0);
  }

  // --- scale + bias + mask, partial max ---
  float m = -1e30f;
#pragma unroll
  for (int jt = 0; jt < 8; jt++){
    int jb = ch*128 + jt*16 + g*4;
    float4 nv = *(const float4*)&negs[jb];
    float4 bv = bvv[jt];
    s[jt][0] = fmaf(s[jt][0], SCALE, bv.x + nv.x);
    s[jt][1] = fmaf(s[jt][1], SCALE, bv.y + nv.y);
    s[jt][2] = fmaf(s[jt][2], SCALE, bv.z + nv.z);
    s[jt][3] = fmaf(s[jt][3], SCALE, bv.w + nv.w);
    m = fmaxf(m, fmaxf(fmaxf(s[jt][0], s[jt][1]), fmaxf(s[jt][2], s[jt][3])));
  }
  m = fmaxf(m, __shfl_xor(m, 16));
  m = fmaxf(m, __shfl_xor(m, 32));
  if (lane < 16) redm[rg][fr][ch] = m;
  __syncthreads();
  m = fmaxf(redm[rg][fr][0], redm[rg][fr][1]);   // global row max

  // --- exp + sum + fused dp/u epilogue ---
  const float* dpb = dp + (size_t)(b*N_ + i0 + i) * (N_*3);
  float sum = 0.f, a0 = 0.f, a1 = 0.f, a2 = 0.f;
#pragma unroll
  for (int jt = 0; jt < 8; jt++){
    int j0 = ch*128 + jt*16 + g*4;
    float p0 = __expf(s[jt][0] - m);
    float p1 = __expf(s[jt][1] - m);
    float p2 = __expf(s[jt][2] - m);
    float p3 = __expf(s[jt][3] - m);
    sum += p0 + p1 + p2 + p3;
    const float4* dq = (const float4*)(dpb + j0*3);
    float4 d0 = dq[0], d1 = dq[1], d2 = dq[2];
    float4 u0v = *(const float4*)&u0s[j0];
    float4 u1v = *(const float4*)&u1s[j0];
    float4 u2v = *(const float4*)&u2s[j0];
    a0 += p0*u0v.x*d0.x + p1*u0v.y*d0.w + p2*u0v.z*d1.z + p3*u0v.w*d2.y;
    a1 += p0*u1v.x*d0.y + p1*u1v.y*d1.x + p2*u1v.z*d1.w + p3*u1v.w*d2.z;
    a2 += p0*u2v.x*d0.z + p1*u2v.y*d1.y + p2*u2v.z*d2.x + p3*u2v.w*d2.w;
  }
  sum += __shfl_xor(sum, 16); sum += __shfl_xor(sum, 32);
  a0  += __shfl_xor(a0, 16);  a0  += __shfl_xor(a0, 32);
  a1  += __shfl_xor(a1, 16);  a1  += __shfl_xor(a1, 32);
  a2  += __shfl_xor(a2, 16);  a2  += __shfl_xor(a2, 32);
  if (lane < 16) redv[rg][fr][ch] = make_float4(sum, a0, a1, a2);
  __syncthreads();

  if (t < 64){
    float4 v0 = redv[t >> 4][t & 15][0];
    float4 v1 = redv[t >> 4][t & 15][1];
    float rs = 1.0f / (v0.x + v1.x);
    float* fp = fpart + ((size_t)(b*NH_ + h)*N_ + i0 + t)*3;
    fp[0] = (v0.y + v1.y)*rs;
    fp[1] = (v0.z + v1.z)*rs;
    fp[2] = (v0.w + v1.w)*rs;
  }
}

// ---------------- final cross-head reduction ----------------
__global__ __launch_bounds__(256) void final_kernel(const float* __restrict__ fpart,
    const float* __restrict__ bf1, const float* __restrict__ bf2, const float* __restrict__ bf3,
    float* __restrict__ out)
{
  int idx = blockIdx.x*256 + threadIdx.x;
  if (idx >= B_*N_*3) return;
  int c = idx % 3;
  int bi = idx / 3;
  int b = bi >> 8, ii = bi & 255;
  float sacc = (c == 0) ? bf1[0] : (c == 1) ? bf2[0] : bf3[0];
#pragma unroll 8
  for (int hh = 0; hh < NH_; hh++){
    sacc += fpart[(((size_t)(b*NH_ + hh))*N_ + ii)*3 + c];
  }
  out[idx] = sacc;
}

extern "C" void kernel_launch(void* const* d_in, const int* in_sizes, int n_in,
                              void* d_out, int out_size, void* d_ws, size_t ws_size,
                              hipStream_t stream)
{
  const float* X    = (const float*)d_in[0];
  const float* bias = (const float*)d_in[1];
  const float* dp   = (const float*)d_in[2];
  const float* mask = (const float*)d_in[3];
  const float* Wi   = (const float*)d_in[4];
  const float* bi   = (const float*)d_in[5];
  const float* Wq   = (const float*)d_in[6];
  const float* bq   = (const float*)d_in[7];
  const float* Wk   = (const float*)d_in[8];
  const float* bk   = (const float*)d_in[9];
  const float* Wv   = (const float*)d_in[10];
  const float* bv   = (const float*)d_in[11];
  const float* Wf1  = (const float*)d_in[12];
  const float* bf1  = (const float*)d_in[13];
  const float* Wf2  = (const float*)d_in[14];
  const float* bf2  = (const float*)d_in[15];
  const float* Wf3  = (const float*)d_in[16];
  const float* bf3  = (const float*)d_in[17];
  float* out = (float*)d_out;

  unsigned short* xb   = (unsigned short*)d_ws;
  unsigned short* wib  = xb   + (size_t)M_*HS_;
  unsigned short* wqb  = wib  + (size_t)HS_*HS_;
  unsigned short* wkb  = wqb  + (size_t)HS_*HS_;
  unsigned short* wvb  = wkb  + (size_t)HS_*HS_;
  unsigned short* hb   = wvb  + (size_t)HS_*HS_;
  unsigned short* qkvb = hb   + (size_t)M_*HS_;
  float* fpart = (float*)(qkvb + (size_t)M_*QKVN);

  {
    int n4 = M_*HS_/4;
    cvt_kernel<<<n4/256, 256, 0, stream>>>(X, xb, n4);
    int w4 = HS_*HS_/4;
    cvt_kernel<<<w4/256, 256, 0, stream>>>(Wi, wib, w4);
    cvt_kernel<<<w4/256, 256, 0, stream>>>(Wq, wqb, w4);
    cvt_kernel<<<w4/256, 256, 0, stream>>>(Wk, wkb, w4);
    cvt_kernel<<<w4/256, 256, 0, stream>>>(Wv, wvb, w4);
  }

  // h = gelu(X Wi^T + bi)
  gemm_bt_kernel<<<(M_/64)*(HS_/64), 256, 0, stream>>>(xb, wib, bi, bi, bi, hb, M_, HS_, HS_, 1);
  // qkv = h [Wq;Wk;Wv]^T + [bq;bk;bv]   (N = 2304)
  gemm_bt_kernel<<<(M_/64)*(QKVN/64), 256, 0, stream>>>(hb, wqb, bq, bk, bv, qkvb, M_, QKVN, HS_, 0);

  attn_kernel<<<B_*NH_*4, 512, 0, stream>>>(qkvb, bias, mask, dp, Wf1, Wf2, Wf3, fpart);

  final_kernel<<<(B_*N_*3 + 255)/256, 256, 0, stream>>>(fpart, bf1, bf2, bf3, out);
}

// Round 4
// 261.947 us; speedup vs baseline: 1.2845x; 1.0607x over previous
//
#include <hip/hip_runtime.h>
#include <hip/hip_fp16.h>

#define B_  32
#define N_  256
#define HS_ 768
#define NH_ 32
#define D_  24
#define M_  (B_*N_)   // 8192
#define QKVN 2304

typedef unsigned short us8 __attribute__((ext_vector_type(8)));
typedef _Float16 f16x8 __attribute__((ext_vector_type(8)));
typedef float f32x4 __attribute__((ext_vector_type(4)));

__device__ __forceinline__ unsigned short f2h(float x){
  return __half_as_ushort(__float2half(x));
}
__device__ __forceinline__ float h2f(unsigned short u){
  return __half2float(__ushort_as_half(u));
}
__device__ __forceinline__ void gload16(const void* g, void* l){
  __builtin_amdgcn_global_load_lds(
      (const __attribute__((address_space(1))) void*)g,
      (__attribute__((address_space(3))) void*)l, 16, 0, 0);
}

// ---------------- fp32 -> fp16-bits conversion ----------------
__global__ __launch_bounds__(256) void cvt_kernel(const float* __restrict__ in,
                                                  unsigned short* __restrict__ out, int n4){
  int i = blockIdx.x*256 + threadIdx.x;
  if (i >= n4) return;
  float4 v = ((const float4*)in)[i];
  ushort4 o;
  o.x = f2h(v.x); o.y = f2h(v.y); o.z = f2h(v.z); o.w = f2h(v.w);
  ((ushort4*)out)[i] = o;
}

// ---------------- GEMM 128x128, BK=32, global_load_lds, swizzled LDS ----------------
// A:(M,K) fp16 row-major, W:(N,K) fp16 row-major, C = A.W^T (+bias, opt gelu), fp16 out.
// LDS tile [128][32] fp16 = 64B rows; chunk swizzle: logical chunk l stored at
// physical p=(l+(row>>1))&3 -> fragment reads are 2-way (free) bank pattern.
__global__ __launch_bounds__(256) void gemm128_kernel(
    const unsigned short* __restrict__ A, const unsigned short* __restrict__ W,
    const float* __restrict__ b0, const float* __restrict__ b1, const float* __restrict__ b2,
    unsigned short* __restrict__ C, int M, int N, int K, int dogelu)
{
  __shared__ unsigned short As[128*32];
  __shared__ unsigned short Bs[128*32];
  int gswz = blockIdx.x;
  int chunkg = gridDim.x >> 3;
  int bid = (gswz & 7)*chunkg + (gswz >> 3);   // XCD-chunked (grid % 8 == 0)
  int tid = threadIdx.x;
  int nT = N >> 7;
  int tm = bid / nT;
  int tn = bid - tm*nT;
  int which = (tn << 7) / 768;
  const float* bp = (which == 0) ? b0 : (which == 1) ? b1 : b2;
  bp -= which * 768;
  int wave = tid >> 6, lane = tid & 63;
  int wm = (wave >> 1) << 6;         // 0 or 64
  int wn = (wave & 1) << 6;          // 0 or 64
  int fr = lane & 15;
  int g  = lane >> 4;                // 0..3

  // staging precompute: two 16B slots per thread per tile
  int ob0 = wave*1024 + lane*16;          // call 0 byte offset in 8KB tile
  int ob1 = ob0 + 4096;                   // call 1
  int r0s = ob0 >> 6, p0 = (ob0 >> 4) & 3, l0 = (p0 - (r0s >> 1)) & 3;
  int r1s = ob1 >> 6, p1 = (ob1 >> 4) & 3, l1 = (p1 - (r1s >> 1)) & 3;
  const char* Ab = (const char*)A;
  const char* Wb = (const char*)W;
  size_t a0off = ((size_t)(tm*128 + r0s)*K)*2 + l0*16;
  size_t a1off = ((size_t)(tm*128 + r1s)*K)*2 + l1*16;
  size_t w0off = ((size_t)(tn*128 + r0s)*K)*2 + l0*16;
  size_t w1off = ((size_t)(tn*128 + r1s)*K)*2 + l1*16;
  char* AsB = (char*)As;
  char* BsB = (char*)Bs;
  int lb0 = wave*1024;          // wave-uniform LDS base, call 0
  int lb1 = lb0 + 4096;

  f32x4 acc[4][4];
#pragma unroll
  for (int m = 0; m < 4; m++)
#pragma unroll
    for (int n = 0; n < 4; n++) acc[m][n] = (f32x4){0.f,0.f,0.f,0.f};

  for (int k0 = 0; k0 < K; k0 += 32){
    size_t kb = (size_t)k0*2;
    gload16(Ab + a0off + kb, AsB + lb0);
    gload16(Ab + a1off + kb, AsB + lb1);
    gload16(Wb + w0off + kb, BsB + lb0);
    gload16(Wb + w1off + kb, BsB + lb1);
    __syncthreads();

    f16x8 af[4], bf[4];
#pragma unroll
    for (int m = 0; m < 4; m++){
      int row = wm + m*16 + fr;
      int ph = (g + (row >> 1)) & 3;
      af[m] = __builtin_bit_cast(f16x8, *(const us8*)(AsB + row*64 + ph*16));
    }
#pragma unroll
    for (int n = 0; n < 4; n++){
      int row = wn + n*16 + fr;
      int ph = (g + (row >> 1)) & 3;
      bf[n] = __builtin_bit_cast(f16x8, *(const us8*)(BsB + row*64 + ph*16));
    }
#pragma unroll
    for (int m = 0; m < 4; m++)
#pragma unroll
      for (int n = 0; n < 4; n++)
        acc[m][n] = __builtin_amdgcn_mfma_f32_16x16x32_f16(af[m], bf[n], acc[m][n], 0, 0, 0);
    __syncthreads();
  }

  // epilogue
#pragma unroll
  for (int n = 0; n < 4; n++){
    int col = tn*128 + wn + n*16 + fr;
    float bv = bp[col];
#pragma unroll
    for (int m = 0; m < 4; m++){
      int row = tm*128 + wm + m*16 + g*4;
#pragma unroll
      for (int q = 0; q < 4; q++){
        float v = acc[m][n][q] + bv;
        if (dogelu) v = 0.5f*v*(1.0f + erff(v*0.70710678118654752f));
        C[(size_t)(row + q)*N + col] = f2h(v);
      }
    }
  }
}

// ---------------- prep: u_c[b,h,j] = sum_d v*Wf_c ; negv[b,j] ----------------
__global__ __launch_bounds__(256) void prep_kernel(
    const unsigned short* __restrict__ qkv, const float* __restrict__ mask,
    const float* __restrict__ Wf1, const float* __restrict__ Wf2, const float* __restrict__ Wf3,
    float* __restrict__ uarr,   // [B*NH][3][N]
    float* __restrict__ negv)   // [B][N]
{
  int bh = blockIdx.x;
  int h = bh & 31, b = bh >> 5;
  int j = threadIdx.x;
  const unsigned short* vr = qkv + (size_t)(b*N_ + j)*QKVN + 1536 + h*D_;
  us8 v0 = *(const us8*)(vr);
  us8 v1 = *(const us8*)(vr + 8);
  us8 v2 = *(const us8*)(vr + 16);
  const float* w1 = Wf1 + h*D_;
  const float* w2 = Wf2 + h*D_;
  const float* w3 = Wf3 + h*D_;
  float u0 = 0.f, u1 = 0.f, u2 = 0.f;
#pragma unroll
  for (int e = 0; e < 8; e++){
    float va = h2f(v0[e]), vb2 = h2f(v1[e]), vc = h2f(v2[e]);
    u0 += va*w1[e] + vb2*w1[8+e] + vc*w1[16+e];
    u1 += va*w2[e] + vb2*w2[8+e] + vc*w2[16+e];
    u2 += va*w3[e] + vb2*w3[8+e] + vc*w3[16+e];
  }
  float* ub = uarr + (size_t)bh*3*N_;
  ub[j] = u0; ub[N_ + j] = u1; ub[2*N_ + j] = u2;
  if (h == 0) negv[b*N_ + j] = (1.0f - mask[b*N_ + j]) * -100000.0f;
}

// ---------------- attention + fused epilogue partials ----------------
// grid: B*NH*4 (XCD-chunk swizzled); block 512 thr = 8 waves; one (b,h), 64 q-rows.
// wave w: row group rg=w>>1 (16 rows), col half ch=w&1 (128 cols).
#define SCALE 0.20412414523193154f  // 24^-0.5
__global__ __launch_bounds__(512, 4) void attn_kernel(
    const unsigned short* __restrict__ qkv,
    const float* __restrict__ bias,
    const float* __restrict__ uarr, const float* __restrict__ negv,
    const float* __restrict__ dp,
    float* __restrict__ fpart)
{
  int gswz = blockIdx.x;
  int lin = (gswz & 7)*512 + (gswz >> 3);   // 4096 = 8*512
  int rb = lin & 3;
  int bh = lin >> 2;
  int h = bh & 31, b = bh >> 5;
  int i0 = rb * 64;
  int t = threadIdx.x;

  __shared__ us8 Kp[256][5];      // 20 KB (chunk3 = zeros, chunk4 pad)
  __shared__ us8 Qp[64][5];       // 5 KB
  __shared__ float u0s[256], u1s[256], u2s[256];
  __shared__ float negs[256];
  __shared__ float redm[4][16][2];
  __shared__ float4 redv[4][16][2];

  us8 z = {0,0,0,0,0,0,0,0};
  if (t < 256){
    const unsigned short* kr = qkv + (size_t)(b*N_ + t)*QKVN + 768 + h*D_;
    Kp[t][0] = *(const us8*)(kr);
    Kp[t][1] = *(const us8*)(kr + 8);
    Kp[t][2] = *(const us8*)(kr + 16);
    Kp[t][3] = z;
  } else if (t < 320){
    int iq = t - 256;
    const unsigned short* qr = qkv + (size_t)(b*N_ + i0 + iq)*QKVN + h*D_;
    Qp[iq][0] = *(const us8*)(qr);
    Qp[iq][1] = *(const us8*)(qr + 8);
    Qp[iq][2] = *(const us8*)(qr + 16);
    Qp[iq][3] = z;
    ((float4*)negs)[iq] = ((const float4*)(negv + b*N_))[iq];
  } else {
    int t2 = t - 320;               // 0..191
    int c = t2 >> 6, q4 = t2 & 63;
    float4 uv = ((const float4*)(uarr + ((size_t)bh*3 + c)*N_))[q4];
    float* dst = (c == 0) ? u0s : (c == 1) ? u1s : u2s;
    ((float4*)dst)[q4] = uv;
  }

  int wave = t >> 6, lane = t & 63;
  int rg = wave >> 1, ch = wave & 1;
  int fr = lane & 15, g = lane >> 4;
  int i = rg*16 + fr;

  // bias prefetch (independent of staging; hides under barrier)
  const float4* bias4 = (const float4*)(bias + ((size_t)(b*NH_ + h)*N_ + i0 + i)*N_ + ch*128);
  float4 bvv[8];
#pragma unroll
  for (int jt = 0; jt < 8; jt++) bvv[jt] = bias4[jt*4 + g];

  __syncthreads();

  // scores via MFMA
  f16x8 qf = __builtin_bit_cast(f16x8, Qp[i][g]);
  f32x4 s[8];
#pragma unroll
  for (int jt = 0; jt < 8; jt++){
    f16x8 kf = __builtin_bit_cast(f16x8, Kp[ch*128 + jt*16 + fr][g]);
    f32x4 zz = {0.f,0.f,0.f,0.f};
    s[jt] = __builtin_amdgcn_mfma_f32_16x16x32_f16(kf, qf, zz, 0, 0, 0);
  }

  // scale + bias + mask, partial max
  float m = -1e30f;
#pragma unroll
  for (int jt = 0; jt < 8; jt++){
    int jb = ch*128 + jt*16 + g*4;
    float4 nv = *(const float4*)&negs[jb];
    float4 bv = bvv[jt];
    s[jt][0] = fmaf(s[jt][0], SCALE, bv.x + nv.x);
    s[jt][1] = fmaf(s[jt][1], SCALE, bv.y + nv.y);
    s[jt][2] = fmaf(s[jt][2], SCALE, bv.z + nv.z);
    s[jt][3] = fmaf(s[jt][3], SCALE, bv.w + nv.w);
    m = fmaxf(m, fmaxf(fmaxf(s[jt][0], s[jt][1]), fmaxf(s[jt][2], s[jt][3])));
  }
  m = fmaxf(m, __shfl_xor(m, 16));
  m = fmaxf(m, __shfl_xor(m, 32));
  if (lane < 16) redm[rg][fr][ch] = m;

  // prefetch dp for jt=0..3 (independent of softmax; hides under barrier)
  const float* dpb = dp + (size_t)(b*N_ + i0 + i) * (N_*3);
  float4 dpre[12];
#pragma unroll
  for (int jt = 0; jt < 4; jt++){
    const float4* dq = (const float4*)(dpb + (ch*128 + jt*16 + g*4)*3);
    dpre[jt*3+0] = dq[0]; dpre[jt*3+1] = dq[1]; dpre[jt*3+2] = dq[2];
  }
  __syncthreads();
  m = fmaxf(redm[rg][fr][0], redm[rg][fr][1]);

  float sum = 0.f, a0 = 0.f, a1 = 0.f, a2 = 0.f;
#pragma unroll
  for (int jt = 0; jt < 8; jt++){
    int j0 = ch*128 + jt*16 + g*4;
    float p0 = __expf(s[jt][0] - m);
    float p1 = __expf(s[jt][1] - m);
    float p2 = __expf(s[jt][2] - m);
    float p3 = __expf(s[jt][3] - m);
    sum += p0 + p1 + p2 + p3;
    float4 d0, d1, d2;
    if (jt < 4){
      d0 = dpre[jt*3+0]; d1 = dpre[jt*3+1]; d2 = dpre[jt*3+2];
    } else {
      const float4* dq = (const float4*)(dpb + j0*3);
      d0 = dq[0]; d1 = dq[1]; d2 = dq[2];
    }
    float4 u0v = *(const float4*)&u0s[j0];
    float4 u1v = *(const float4*)&u1s[j0];
    float4 u2v = *(const float4*)&u2s[j0];
    a0 += p0*u0v.x*d0.x + p1*u0v.y*d0.w + p2*u0v.z*d1.z + p3*u0v.w*d2.y;
    a1 += p0*u1v.x*d0.y + p1*u1v.y*d1.x + p2*u1v.z*d1.w + p3*u1v.w*d2.z;
    a2 += p0*u2v.x*d0.z + p1*u2v.y*d1.y + p2*u2v.z*d2.x + p3*u2v.w*d2.w;
  }
  sum += __shfl_xor(sum, 16); sum += __shfl_xor(sum, 32);
  a0  += __shfl_xor(a0, 16);  a0  += __shfl_xor(a0, 32);
  a1  += __shfl_xor(a1, 16);  a1  += __shfl_xor(a1, 32);
  a2  += __shfl_xor(a2, 16);  a2  += __shfl_xor(a2, 32);
  if (lane < 16) redv[rg][fr][ch] = make_float4(sum, a0, a1, a2);
  __syncthreads();

  if (t < 64){
    float4 v0 = redv[t >> 4][t & 15][0];
    float4 v1 = redv[t >> 4][t & 15][1];
    float rs = 1.0f / (v0.x + v1.x);
    float* fp = fpart + ((size_t)(b*NH_ + h)*N_ + i0 + t)*3;
    fp[0] = (v0.y + v1.y)*rs;
    fp[1] = (v0.z + v1.z)*rs;
    fp[2] = (v0.w + v1.w)*rs;
  }
}

// ---------------- final cross-head reduction ----------------
__global__ __launch_bounds__(256) void final_kernel(const float* __restrict__ fpart,
    const float* __restrict__ bf1, const float* __restrict__ bf2, const float* __restrict__ bf3,
    float* __restrict__ out)
{
  int idx = blockIdx.x*256 + threadIdx.x;
  if (idx >= B_*N_*3) return;
  int c = idx % 3;
  int bi = idx / 3;
  int b = bi >> 8, ii = bi & 255;
  float sacc = (c == 0) ? bf1[0] : (c == 1) ? bf2[0] : bf3[0];
#pragma unroll 8
  for (int hh = 0; hh < NH_; hh++){
    sacc += fpart[(((size_t)(b*NH_ + hh))*N_ + ii)*3 + c];
  }
  out[idx] = sacc;
}

extern "C" void kernel_launch(void* const* d_in, const int* in_sizes, int n_in,
                              void* d_out, int out_size, void* d_ws, size_t ws_size,
                              hipStream_t stream)
{
  const float* X    = (const float*)d_in[0];
  const float* bias = (const float*)d_in[1];
  const float* dp   = (const float*)d_in[2];
  const float* mask = (const float*)d_in[3];
  const float* Wi   = (const float*)d_in[4];
  const float* bi   = (const float*)d_in[5];
  const float* Wq   = (const float*)d_in[6];
  const float* bq   = (const float*)d_in[7];
  const float* Wk   = (const float*)d_in[8];
  const float* bk   = (const float*)d_in[9];
  const float* Wv   = (const float*)d_in[10];
  const float* bv   = (const float*)d_in[11];
  const float* Wf1  = (const float*)d_in[12];
  const float* bf1  = (const float*)d_in[13];
  const float* Wf2  = (const float*)d_in[14];
  const float* bf2  = (const float*)d_in[15];
  const float* Wf3  = (const float*)d_in[16];
  const float* bf3  = (const float*)d_in[17];
  float* out = (float*)d_out;

  unsigned short* xb   = (unsigned short*)d_ws;
  unsigned short* wib  = xb   + (size_t)M_*HS_;
  unsigned short* wqb  = wib  + (size_t)HS_*HS_;
  unsigned short* wkb  = wqb  + (size_t)HS_*HS_;
  unsigned short* wvb  = wkb  + (size_t)HS_*HS_;
  unsigned short* hb   = wvb  + (size_t)HS_*HS_;
  unsigned short* qkvb = hb   + (size_t)M_*HS_;
  float* fpart = (float*)(qkvb + (size_t)M_*QKVN);
  float* uarr  = fpart + (size_t)B_*NH_*N_*3;
  float* negv  = uarr + (size_t)B_*NH_*3*N_;

  {
    int n4 = M_*HS_/4;
    cvt_kernel<<<n4/256, 256, 0, stream>>>(X, xb, n4);
    int w4 = HS_*HS_/4;
    cvt_kernel<<<w4/256, 256, 0, stream>>>(Wi, wib, w4);
    cvt_kernel<<<w4/256, 256, 0, stream>>>(Wq, wqb, w4);
    cvt_kernel<<<w4/256, 256, 0, stream>>>(Wk, wkb, w4);
    cvt_kernel<<<w4/256, 256, 0, stream>>>(Wv, wvb, w4);
  }

  // h = gelu(X Wi^T + bi):  grid 64*6 = 384 (%8==0)
  gemm128_kernel<<<(M_/128)*(HS_/128), 256, 0, stream>>>(xb, wib, bi, bi, bi, hb, M_, HS_, HS_, 1);
  // qkv = h [Wq;Wk;Wv]^T + bias:  grid 64*18 = 1152 (%8==0)
  gemm128_kernel<<<(M_/128)*(QKVN/128), 256, 0, stream>>>(hb, wqb, bq, bk, bv, qkvb, M_, QKVN, HS_, 0);

  prep_kernel<<<B_*NH_, 256, 0, stream>>>(qkvb, mask, Wf1, Wf2, Wf3, uarr, negv);

  attn_kernel<<<B_*NH_*4, 512, 0, stream>>>(qkvb, bias, uarr, negv, dp, fpart);

  final_kernel<<<(B_*N_*3 + 255)/256, 256, 0, stream>>>(fpart, bf1, bf2, bf3, out);
}

// Round 5
// 248.229 us; speedup vs baseline: 1.3555x; 1.0553x over previous
//
#include <hip/hip_runtime.h>
#include <hip/hip_fp16.h>

#define B_  32
#define N_  256
#define HS_ 768
#define NH_ 32
#define D_  24
#define M_  (B_*N_)   // 8192
#define QKVN 2304

typedef unsigned short us8 __attribute__((ext_vector_type(8)));
typedef _Float16 f16x8 __attribute__((ext_vector_type(8)));
typedef float f32x4 __attribute__((ext_vector_type(4)));

__device__ __forceinline__ unsigned short f2h(float x){
  return __half_as_ushort(__float2half(x));
}
__device__ __forceinline__ float h2f(unsigned short u){
  return __half2float(__ushort_as_half(u));
}
__device__ __forceinline__ void gload16(const void* g, void* l){
  __builtin_amdgcn_global_load_lds(
      (const __attribute__((address_space(1))) void*)g,
      (__attribute__((address_space(3))) void*)l, 16, 0, 0);
}

// ---------------- fp32 -> fp16-bits conversion ----------------
__global__ __launch_bounds__(256) void cvt_kernel(const float* __restrict__ in,
                                                  unsigned short* __restrict__ out, int n4){
  int i = blockIdx.x*256 + threadIdx.x;
  if (i >= n4) return;
  float4 v = ((const float4*)in)[i];
  ushort4 o;
  o.x = f2h(v.x); o.y = f2h(v.y); o.z = f2h(v.z); o.w = f2h(v.w);
  ((ushort4*)out)[i] = o;
}

// ---------------- GEMM 128x128, BK=64, global_load_lds, XOR-swizzled LDS ----------------
// A:(M,K) fp16 row-major, W:(N,K) fp16 row-major, C = A.W^T (+bias, opt gelu), fp16 out.
// LDS tile [128][64] fp16 = 128B rows = 8 chunks of 16B; chunk swizzle p = l ^ (row&7).
// global_load_lds writes linear; source address pre-swizzled (both-sides rule).
__global__ __launch_bounds__(256) void gemm128_kernel(
    const unsigned short* __restrict__ A, const unsigned short* __restrict__ W,
    const float* __restrict__ b0, const float* __restrict__ b1, const float* __restrict__ b2,
    unsigned short* __restrict__ C, int M, int N, int K, int dogelu)
{
  __shared__ unsigned short As[128*64];
  __shared__ unsigned short Bs[128*64];
  int gswz = blockIdx.x;
  int chunkg = gridDim.x >> 3;
  int bid = (gswz & 7)*chunkg + (gswz >> 3);   // XCD-chunked (grid % 8 == 0)
  int tid = threadIdx.x;
  int nT = N >> 7;
  int tm = bid / nT;
  int tn = bid - tm*nT;
  int which = (tn << 7) / 768;
  const float* bp = (which == 0) ? b0 : (which == 1) ? b1 : b2;
  bp -= which * 768;
  int wave = tid >> 6, lane = tid & 63;
  int wm = (wave >> 1) << 6;         // 0 or 64
  int wn = (wave & 1) << 6;          // 0 or 64
  int fr = lane & 15;
  int g  = lane >> 4;                // 0..3

  // staging: 4 slots/thread/matrix; slot s -> LDS byte ob = s*4096 + tid*16
  size_t aoff[4], woff[4];
  int ldsb[4];
#pragma unroll
  for (int s4 = 0; s4 < 4; s4++){
    int ob = s4*4096 + tid*16;
    int r  = ob >> 7;                 // LDS row
    int p  = (ob >> 4) & 7;           // physical chunk
    int l  = p ^ (r & 7);             // logical chunk (global)
    aoff[s4] = ((size_t)(tm*128 + r)*K)*2 + l*16;
    woff[s4] = ((size_t)(tn*128 + r)*K)*2 + l*16;
    ldsb[s4] = s4*4096 + wave*1024;   // wave-uniform base (hw adds lane*16)
  }
  const char* Ab = (const char*)A;
  const char* Wb = (const char*)W;
  char* AsB = (char*)As;
  char* BsB = (char*)Bs;

  f32x4 acc[4][4];
#pragma unroll
  for (int m = 0; m < 4; m++)
#pragma unroll
    for (int n = 0; n < 4; n++) acc[m][n] = (f32x4){0.f,0.f,0.f,0.f};

  int swA = 0, swB = 0;  // silence unused warnings pattern (no-op)
  (void)swA; (void)swB;

  for (int k0 = 0; k0 < K; k0 += 64){
    size_t kb = (size_t)k0*2;
#pragma unroll
    for (int s4 = 0; s4 < 4; s4++) gload16(Ab + aoff[s4] + kb, AsB + ldsb[s4]);
#pragma unroll
    for (int s4 = 0; s4 < 4; s4++) gload16(Wb + woff[s4] + kb, BsB + ldsb[s4]);
    __syncthreads();

    f16x8 af[4], bf[4];
#pragma unroll
    for (int m = 0; m < 4; m++){
      int row = wm + m*16 + fr;
      af[m] = __builtin_bit_cast(f16x8, *(const us8*)(AsB + row*128 + ((g ^ (row & 7))*16)));
    }
#pragma unroll
    for (int n = 0; n < 4; n++){
      int row = wn + n*16 + fr;
      bf[n] = __builtin_bit_cast(f16x8, *(const us8*)(BsB + row*128 + ((g ^ (row & 7))*16)));
    }
#pragma unroll
    for (int m = 0; m < 4; m++)
#pragma unroll
      for (int n = 0; n < 4; n++)
        acc[m][n] = __builtin_amdgcn_mfma_f32_16x16x32_f16(af[m], bf[n], acc[m][n], 0, 0, 0);

    // second K-half: chunks g+4 (phys = first ^ 4)
#pragma unroll
    for (int m = 0; m < 4; m++){
      int row = wm + m*16 + fr;
      af[m] = __builtin_bit_cast(f16x8, *(const us8*)(AsB + row*128 + (((g+4) ^ (row & 7))*16)));
    }
#pragma unroll
    for (int n = 0; n < 4; n++){
      int row = wn + n*16 + fr;
      bf[n] = __builtin_bit_cast(f16x8, *(const us8*)(BsB + row*128 + (((g+4) ^ (row & 7))*16)));
    }
#pragma unroll
    for (int m = 0; m < 4; m++)
#pragma unroll
      for (int n = 0; n < 4; n++)
        acc[m][n] = __builtin_amdgcn_mfma_f32_16x16x32_f16(af[m], bf[n], acc[m][n], 0, 0, 0);
    __syncthreads();
  }

  // epilogue
#pragma unroll
  for (int n = 0; n < 4; n++){
    int col = tn*128 + wn + n*16 + fr;
    float bv = bp[col];
#pragma unroll
    for (int m = 0; m < 4; m++){
      int row = tm*128 + wm + m*16 + g*4;
#pragma unroll
      for (int q = 0; q < 4; q++){
        float v = acc[m][n][q] + bv;
        if (dogelu) v = 0.5f*v*(1.0f + erff(v*0.70710678118654752f));
        C[(size_t)(row + q)*N + col] = f2h(v);
      }
    }
  }
}

// ---------------- prep: u_c[b,h,j] = sum_d v*Wf_c ; negv[b,j] ----------------
__global__ __launch_bounds__(256) void prep_kernel(
    const unsigned short* __restrict__ qkv, const float* __restrict__ mask,
    const float* __restrict__ Wf1, const float* __restrict__ Wf2, const float* __restrict__ Wf3,
    float* __restrict__ uarr,   // [B*NH][3][N]
    float* __restrict__ negv)   // [B][N]
{
  int bh = blockIdx.x;
  int h = bh & 31, b = bh >> 5;
  int j = threadIdx.x;
  const unsigned short* vr = qkv + (size_t)(b*N_ + j)*QKVN + 1536 + h*D_;
  us8 v0 = *(const us8*)(vr);
  us8 v1 = *(const us8*)(vr + 8);
  us8 v2 = *(const us8*)(vr + 16);
  const float* w1 = Wf1 + h*D_;
  const float* w2 = Wf2 + h*D_;
  const float* w3 = Wf3 + h*D_;
  float u0 = 0.f, u1 = 0.f, u2 = 0.f;
#pragma unroll
  for (int e = 0; e < 8; e++){
    float va = h2f(v0[e]), vb2 = h2f(v1[e]), vc = h2f(v2[e]);
    u0 += va*w1[e] + vb2*w1[8+e] + vc*w1[16+e];
    u1 += va*w2[e] + vb2*w2[8+e] + vc*w2[16+e];
    u2 += va*w3[e] + vb2*w3[8+e] + vc*w3[16+e];
  }
  float* ub = uarr + (size_t)bh*3*N_;
  ub[j] = u0; ub[N_ + j] = u1; ub[2*N_ + j] = u2;
  if (h == 0) negv[b*N_ + j] = (1.0f - mask[b*N_ + j]) * -100000.0f;
}

// ---------------- attention + fused epilogue partials ----------------
// grid: B*NH*4 (XCD-chunk swizzled); block 512 thr = 8 waves; one (b,h), 64 q-rows.
// wave w: row group rg=w>>1 (16 rows), col half ch=w&1 (128 cols).
// bias+neg folded into MFMA C-in (scaled by sqrt(24)); rescaled inside exp.
#define SCALE 0.20412414523193154f   // 24^-0.5
#define INVSCALE 4.898979485566356f  // sqrt(24)
__global__ __launch_bounds__(512, 4) void attn_kernel(
    const unsigned short* __restrict__ qkv,
    const float* __restrict__ bias,
    const float* __restrict__ uarr, const float* __restrict__ negv,
    const float* __restrict__ dp,
    float* __restrict__ fpart)
{
  int gswz = blockIdx.x;
  int lin = (gswz & 7)*512 + (gswz >> 3);   // 4096 = 8*512
  int rb = lin & 3;
  int bh = lin >> 2;
  int h = bh & 31, b = bh >> 5;
  int i0 = rb * 64;
  int t = threadIdx.x;

  __shared__ us8 Kp[256][5];      // 20 KB (chunk3 = zeros, chunk4 pad)
  __shared__ us8 Qp[64][5];       // 5 KB
  __shared__ float u0s[256], u1s[256], u2s[256];
  __shared__ float negs[256];
  __shared__ float redm[4][16][2];
  __shared__ float4 redv[4][16][2];

  us8 z = {0,0,0,0,0,0,0,0};
  if (t < 256){
    const unsigned short* kr = qkv + (size_t)(b*N_ + t)*QKVN + 768 + h*D_;
    Kp[t][0] = *(const us8*)(kr);
    Kp[t][1] = *(const us8*)(kr + 8);
    Kp[t][2] = *(const us8*)(kr + 16);
    Kp[t][3] = z;
  } else if (t < 320){
    int iq = t - 256;
    const unsigned short* qr = qkv + (size_t)(b*N_ + i0 + iq)*QKVN + h*D_;
    Qp[iq][0] = *(const us8*)(qr);
    Qp[iq][1] = *(const us8*)(qr + 8);
    Qp[iq][2] = *(const us8*)(qr + 16);
    Qp[iq][3] = z;
    ((float4*)negs)[iq] = ((const float4*)(negv + b*N_))[iq];
  } else {
    int t2 = t - 320;               // 0..191
    int c = t2 >> 6, q4 = t2 & 63;
    float4 uv = ((const float4*)(uarr + ((size_t)bh*3 + c)*N_))[q4];
    float* dst = (c == 0) ? u0s : (c == 1) ? u1s : u2s;
    ((float4*)dst)[q4] = uv;
  }

  int wave = t >> 6, lane = t & 63;
  int rg = wave >> 1, ch = wave & 1;
  int fr = lane & 15, g = lane >> 4;
  int i = rg*16 + fr;

  // bias prefetch (independent of staging; in flight across the barrier)
  const float4* bias4 = (const float4*)(bias + ((size_t)(b*NH_ + h)*N_ + i0 + i)*N_ + ch*128);
  float4 bvv[8];
#pragma unroll
  for (int jt = 0; jt < 8; jt++) bvv[jt] = bias4[jt*4 + g];

  __syncthreads();

  // scores: s_raw = q.k + (bias+neg)*sqrt(24); true score = s_raw * SCALE
  f16x8 qf = __builtin_bit_cast(f16x8, Qp[i][g]);
  f32x4 s[8];
#pragma unroll
  for (int jt = 0; jt < 8; jt++){
    int jb = ch*128 + jt*16 + g*4;
    float4 nv = *(const float4*)&negs[jb];
    float4 bv = bvv[jt];
    f32x4 cin;
    cin[0] = (bv.x + nv.x)*INVSCALE;
    cin[1] = (bv.y + nv.y)*INVSCALE;
    cin[2] = (bv.z + nv.z)*INVSCALE;
    cin[3] = (bv.w + nv.w)*INVSCALE;
    f16x8 kf = __builtin_bit_cast(f16x8, Kp[ch*128 + jt*16 + fr][g]);
    s[jt] = __builtin_amdgcn_mfma_f32_16x16x32_f16(kf, qf, cin, 0, 0, 0);
  }

  // partial row max (raw units)
  float m = -3.0e38f;
#pragma unroll
  for (int jt = 0; jt < 8; jt++)
    m = fmaxf(m, fmaxf(fmaxf(s[jt][0], s[jt][1]), fmaxf(s[jt][2], s[jt][3])));
  m = fmaxf(m, __shfl_xor(m, 16));
  m = fmaxf(m, __shfl_xor(m, 32));
  if (lane < 16) redm[rg][fr][ch] = m;
  __syncthreads();
  m = fmaxf(redm[rg][fr][0], redm[rg][fr][1]);   // global row max (raw)

  // exp((raw-m)*SCALE), sum, fused dp/u epilogue
  const float* dpb = dp + (size_t)(b*N_ + i0 + i) * (N_*3);
  float sum = 0.f, a0 = 0.f, a1 = 0.f, a2 = 0.f;
#pragma unroll
  for (int jt = 0; jt < 8; jt++){
    int j0 = ch*128 + jt*16 + g*4;
    float p0 = __expf((s[jt][0] - m)*SCALE);
    float p1 = __expf((s[jt][1] - m)*SCALE);
    float p2 = __expf((s[jt][2] - m)*SCALE);
    float p3 = __expf((s[jt][3] - m)*SCALE);
    sum += p0 + p1 + p2 + p3;
    const float4* dq = (const float4*)(dpb + j0*3);
    float4 d0 = dq[0], d1 = dq[1], d2 = dq[2];
    float4 u0v = *(const float4*)&u0s[j0];
    float4 u1v = *(const float4*)&u1s[j0];
    float4 u2v = *(const float4*)&u2s[j0];
    a0 += p0*u0v.x*d0.x + p1*u0v.y*d0.w + p2*u0v.z*d1.z + p3*u0v.w*d2.y;
    a1 += p0*u1v.x*d0.y + p1*u1v.y*d1.x + p2*u1v.z*d1.w + p3*u1v.w*d2.z;
    a2 += p0*u2v.x*d0.z + p1*u2v.y*d1.y + p2*u2v.z*d2.x + p3*u2v.w*d2.w;
  }
  sum += __shfl_xor(sum, 16); sum += __shfl_xor(sum, 32);
  a0  += __shfl_xor(a0, 16);  a0  += __shfl_xor(a0, 32);
  a1  += __shfl_xor(a1, 16);  a1  += __shfl_xor(a1, 32);
  a2  += __shfl_xor(a2, 16);  a2  += __shfl_xor(a2, 32);
  if (lane < 16) redv[rg][fr][ch] = make_float4(sum, a0, a1, a2);
  __syncthreads();

  if (t < 64){
    float4 v0 = redv[t >> 4][t & 15][0];
    float4 v1 = redv[t >> 4][t & 15][1];
    float rs = 1.0f / (v0.x + v1.x);
    float* fp = fpart + ((size_t)(b*NH_ + h)*N_ + i0 + t)*3;
    fp[0] = (v0.y + v1.y)*rs;
    fp[1] = (v0.z + v1.z)*rs;
    fp[2] = (v0.w + v1.w)*rs;
  }
}

// ---------------- final cross-head reduction ----------------
__global__ __launch_bounds__(256) void final_kernel(const float* __restrict__ fpart,
    const float* __restrict__ bf1, const float* __restrict__ bf2, const float* __restrict__ bf3,
    float* __restrict__ out)
{
  int idx = blockIdx.x*256 + threadIdx.x;
  if (idx >= B_*N_*3) return;
  int c = idx % 3;
  int bi = idx / 3;
  int b = bi >> 8, ii = bi & 255;
  float sacc = (c == 0) ? bf1[0] : (c == 1) ? bf2[0] : bf3[0];
#pragma unroll 8
  for (int hh = 0; hh < NH_; hh++){
    sacc += fpart[(((size_t)(b*NH_ + hh))*N_ + ii)*3 + c];
  }
  out[idx] = sacc;
}

extern "C" void kernel_launch(void* const* d_in, const int* in_sizes, int n_in,
                              void* d_out, int out_size, void* d_ws, size_t ws_size,
                              hipStream_t stream)
{
  const float* X    = (const float*)d_in[0];
  const float* bias = (const float*)d_in[1];
  const float* dp   = (const float*)d_in[2];
  const float* mask = (const float*)d_in[3];
  const float* Wi   = (const float*)d_in[4];
  const float* bi   = (const float*)d_in[5];
  const float* Wq   = (const float*)d_in[6];
  const float* bq   = (const float*)d_in[7];
  const float* Wk   = (const float*)d_in[8];
  const float* bk   = (const float*)d_in[9];
  const float* Wv   = (const float*)d_in[10];
  const float* bv   = (const float*)d_in[11];
  const float* Wf1  = (const float*)d_in[12];
  const float* bf1  = (const float*)d_in[13];
  const float* Wf2  = (const float*)d_in[14];
  const float* bf2  = (const float*)d_in[15];
  const float* Wf3  = (const float*)d_in[16];
  const float* bf3  = (const float*)d_in[17];
  float* out = (float*)d_out;

  unsigned short* xb   = (unsigned short*)d_ws;
  unsigned short* wib  = xb   + (size_t)M_*HS_;
  unsigned short* wqb  = wib  + (size_t)HS_*HS_;
  unsigned short* wkb  = wqb  + (size_t)HS_*HS_;
  unsigned short* wvb  = wkb  + (size_t)HS_*HS_;
  unsigned short* hb   = wvb  + (size_t)HS_*HS_;
  unsigned short* qkvb = hb   + (size_t)M_*HS_;
  float* fpart = (float*)(qkvb + (size_t)M_*QKVN);
  float* uarr  = fpart + (size_t)B_*NH_*N_*3;
  float* negv  = uarr + (size_t)B_*NH_*3*N_;

  {
    int n4 = M_*HS_/4;
    cvt_kernel<<<n4/256, 256, 0, stream>>>(X, xb, n4);
    int w4 = HS_*HS_/4;
    cvt_kernel<<<w4/256, 256, 0, stream>>>(Wi, wib, w4);
    cvt_kernel<<<w4/256, 256, 0, stream>>>(Wq, wqb, w4);
    cvt_kernel<<<w4/256, 256, 0, stream>>>(Wk, wkb, w4);
    cvt_kernel<<<w4/256, 256, 0, stream>>>(Wv, wvb, w4);
  }

  // h = gelu(X Wi^T + bi):  grid 64*6 = 384 (%8==0)
  gemm128_kernel<<<(M_/128)*(HS_/128), 256, 0, stream>>>(xb, wib, bi, bi, bi, hb, M_, HS_, HS_, 1);
  // qkv = h [Wq;Wk;Wv]^T + bias:  grid 64*18 = 1152 (%8==0)
  gemm128_kernel<<<(M_/128)*(QKVN/128), 256, 0, stream>>>(hb, wqb, bq, bk, bv, qkvb, M_, QKVN, HS_, 0);

  prep_kernel<<<B_*NH_, 256, 0, stream>>>(qkvb, mask, Wf1, Wf2, Wf3, uarr, negv);

  attn_kernel<<<B_*NH_*4, 512, 0, stream>>>(qkvb, bias, uarr, negv, dp, fpart);

  final_kernel<<<(B_*N_*3 + 255)/256, 256, 0, stream>>>(fpart, bf1, bf2, bf3, out);
}